// Round 1
// 569.286 us; speedup vs baseline: 1.0294x; 1.0294x over previous
//
#include <hip/hip_runtime.h>
#include <hip/hip_bf16.h>

// TopKPool: N=8192 nodes, F=256 features, k=4096 kept.
// out = [X_pooled (4096x256 f32) | A_pooled (4096x4096 f32)]
// A_pooled = A[idx,:] @ A[:,idx] (0.275 TFLOP) instead of (A@A)[idx][:,idx].
// Round 4: (a) gemm_fp8 -> 2-phase double-buffered LDS with raw s_barrier +
// counted vmcnt(8) so next-tile global_load_lds stays in flight during MFMA
// (__syncthreads was forcing a vmcnt(0) drain every K-tile -> MfmaUtil 32%).
// (b) topk -> 4-pass radix-256 select (was 32-iteration binary search with
// ~100 block-wide barrier rounds on a single CU).

#define N_NODES 8192
#define F_DIM   256
#define K_SEL   4096

typedef float floatx4 __attribute__((ext_vector_type(4)));
typedef int   intx4   __attribute__((ext_vector_type(4)));
typedef int   intx8   __attribute__((ext_vector_type(8)));

__device__ __forceinline__ void async_copy16(const void* g, void* l) {
  __builtin_amdgcn_global_load_lds((const __attribute__((address_space(1))) void*)g,
                                   (__attribute__((address_space(3))) void*)l,
                                   16, 0, 0);
}

// ---------------- y = X @ (p / ||p||) : one wave per row ----------------
__global__ __launch_bounds__(256) void compute_y(const float* __restrict__ X,
                                                 const float* __restrict__ p,
                                                 float* __restrict__ y) {
  __shared__ __align__(16) float s_p[F_DIM];
  __shared__ float s_part[4];
  __shared__ float s_inv;
  const int tid = threadIdx.x;
  float pv = p[tid];
  s_p[tid] = pv;
  float sq = pv * pv;
  #pragma unroll
  for (int off = 32; off > 0; off >>= 1) sq += __shfl_down(sq, off, 64);
  if ((tid & 63) == 0) s_part[tid >> 6] = sq;
  __syncthreads();
  if (tid == 0) s_inv = rsqrtf(s_part[0] + s_part[1] + s_part[2] + s_part[3]);
  __syncthreads();
  const int wave = tid >> 6, lane = tid & 63;
  const int row = blockIdx.x * 4 + wave;
  const float4* xr = (const float4*)(X + (size_t)row * F_DIM);
  const float4* pr = (const float4*)s_p;
  float4 xv = xr[lane];
  float4 pw = pr[lane];
  float d = xv.x * pw.x + xv.y * pw.y + xv.z * pw.z + xv.w * pw.w;
  #pragma unroll
  for (int off = 32; off > 0; off >>= 1) d += __shfl_down(d, off, 64);
  if (lane == 0) y[row] = d * s_inv;
}

// ---------------- exact top-k via radix-256 select ----------------
// rank[i] = position among kept nodes in ascending-index order, or -1.
// Ties at threshold keep lowest indices (matches top_k stability + sort).

__device__ __forceinline__ unsigned block_exscan_fast(unsigned tv, unsigned* wred,
                                                      int tid, int lane, int wid) {
  unsigned v = tv;
  #pragma unroll
  for (int o = 1; o < 64; o <<= 1) {
    unsigned n = __shfl_up(v, o, 64);
    if (lane >= o) v += n;
  }
  if (lane == 63) wred[wid] = v;
  __syncthreads();
  unsigned off = 0;
  #pragma unroll
  for (int w = 0; w < 16; ++w) off += (w < wid) ? wred[w] : 0u;
  __syncthreads();  // wred reused by caller / next call
  return off + v - tv;
}

__global__ __launch_bounds__(1024) void topk_radix(const float* __restrict__ y,
                                                   int* __restrict__ rank) {
  __shared__ unsigned keys[N_NODES];   // 32 KB
  __shared__ unsigned hist[256];
  __shared__ unsigned wred[16];
  __shared__ unsigned s_pref, s_krem;
  const int tid = threadIdx.x;
  const int lane = tid & 63;
  const int wid = tid >> 6;
  for (int i = tid; i < N_NODES; i += 1024) {
    unsigned u = __float_as_uint(y[i]);
    keys[i] = (u & 0x80000000u) ? ~u : (u | 0x80000000u);  // monotone map
  }
  if (tid == 0) { s_pref = 0u; s_krem = (unsigned)K_SEL; }
  __syncthreads();

  // 4 passes over 8-bit digits, MSB first. Each pass: histogram of keys
  // matching the known prefix, suffix-count scan, pick the digit bucket
  // containing the K-th largest, recurse.
  #pragma unroll
  for (int shift = 24; shift >= 0; shift -= 8) {
    if (tid < 256) hist[tid] = 0u;
    const unsigned pref = s_pref;
    const unsigned krem = s_krem;
    __syncthreads();
    const unsigned pmask = (shift == 24) ? 0u : (0xFFFFFFFFu << (shift + 8));
    for (int i = tid; i < N_NODES; i += 1024) {
      unsigned k = keys[i];
      if ((k & pmask) == pref) atomicAdd(&hist[(k >> shift) & 255u], 1u);
    }
    __syncthreads();
    // cnt_ge[b] = #(digit >= b) via reversed wave-inclusive scans (bins 255-tid)
    unsigned v = (tid < 256) ? hist[255 - tid] : 0u;
    #pragma unroll
    for (int o = 1; o < 64; o <<= 1) {
      unsigned n = __shfl_up(v, o, 64);
      if (lane >= o) v += n;
    }
    if (tid < 256 && lane == 63) wred[wid] = v;
    __syncthreads();
    if (tid < 256) {
      unsigned off = 0;
      #pragma unroll
      for (int w = 0; w < 4; ++w) off += (w < wid) ? wred[w] : 0u;
      const unsigned cge = v + off;              // #(prefix match, digit >= b)
      const unsigned b = 255u - (unsigned)tid;
      const unsigned cgt = cge - hist[b];        // #(prefix match, digit > b)
      if (cgt < krem && cge >= krem) {           // unique winning bucket
        s_pref = pref | (b << shift);
        s_krem = krem - cgt;
      }
    }
    __syncthreads();
  }

  const unsigned T = s_pref;        // exact K-th largest key value
  const unsigned need_eq = s_krem;  // how many ==T keys to keep (lowest idx)

  const int base = tid << 3;
  unsigned e[8], g[8], te = 0;
  #pragma unroll
  for (int j = 0; j < 8; ++j) {
    unsigned k = keys[base + j];
    e[j] = (k == T) ? 1u : 0u;
    g[j] = (k > T) ? 1u : 0u;
    te += e[j];
  }
  unsigned eqr = block_exscan_fast(te, wred, tid, lane, wid);
  unsigned keep[8], tk = 0;
  #pragma unroll
  for (int j = 0; j < 8; ++j) {
    unsigned kp = g[j] | (e[j] & ((eqr < need_eq) ? 1u : 0u));
    eqr += e[j];
    keep[j] = kp;
    tk += kp;
  }
  unsigned pos = block_exscan_fast(tk, wred, tid, lane, wid);
  #pragma unroll
  for (int j = 0; j < 8; ++j) {
    if (keep[j]) { rank[base + j] = (int)pos; pos++; }
    else rank[base + j] = -1;
  }
}

// ---------------- fused gather -> fp8: one pass over A ----------------
// Abf8[rank[r], c] = e4m3(A[r, c])   (selected rows, K contiguous)
// Bt8 [rank[c], r] = e4m3(A[r, c])   (selected cols, transposed)
__global__ __launch_bounds__(256) void gather_both(const float* __restrict__ A,
                                                   const int* __restrict__ rank,
                                                   unsigned char* __restrict__ Abf8,
                                                   unsigned char* __restrict__ Bt8) {
  __shared__ float tile[64][65];
  __shared__ int rr_[64], rc_[64];
  const int tid = threadIdx.x;
  const int r0 = blockIdx.y << 6, c0 = blockIdx.x << 6;
  if (tid < 64) rr_[tid] = rank[r0 + tid];
  else if (tid < 128) rc_[tid - 64] = rank[c0 + tid - 64];
  const int trow = tid >> 4, tc4 = (tid & 15) << 2;
  #pragma unroll
  for (int i = 0; i < 4; ++i) {
    const float4 v = *(const float4*)(A + (size_t)(r0 + trow + i * 16) * N_NODES + c0 + tc4);
    tile[trow + i * 16][tc4 + 0] = v.x;
    tile[trow + i * 16][tc4 + 1] = v.y;
    tile[trow + i * 16][tc4 + 2] = v.z;
    tile[trow + i * 16][tc4 + 3] = v.w;
  }
  __syncthreads();
  const int wv = tid >> 6, ln = tid & 63;
  const int sub = ln >> 4, m4 = (ln & 15) << 2;
  // rows -> Abf8 (4B packed stores)
  #pragma unroll
  for (int t = 0; t < 4; ++t) {
    int row = (wv << 4) + (t << 2) + sub;
    int rk = rr_[row];
    if (rk >= 0) {
      int v = __builtin_amdgcn_cvt_pk_fp8_f32(tile[row][m4 + 0], tile[row][m4 + 1], 0, false);
      v = __builtin_amdgcn_cvt_pk_fp8_f32(tile[row][m4 + 2], tile[row][m4 + 3], v, true);
      *(int*)(Abf8 + (size_t)rk * N_NODES + c0 + m4) = v;
    }
  }
  // cols -> Bt8 (transposed, 4B packed stores)
  #pragma unroll
  for (int t = 0; t < 4; ++t) {
    int col = (wv << 4) + (t << 2) + sub;
    int rk = rc_[col];
    if (rk >= 0) {
      int v = __builtin_amdgcn_cvt_pk_fp8_f32(tile[m4 + 0][col], tile[m4 + 1][col], 0, false);
      v = __builtin_amdgcn_cvt_pk_fp8_f32(tile[m4 + 2][col], tile[m4 + 3][col], v, true);
      *(int*)(Bt8 + (size_t)rk * N_NODES + r0 + m4) = v;
    }
  }
}

// ---------------- X_pooled[rank[i],:] = X[i,:] * tanh(y[i]) ----------------
__global__ __launch_bounds__(256) void x_pool(const float* __restrict__ X,
                                              const float* __restrict__ y,
                                              const int* __restrict__ rank,
                                              float* __restrict__ out0) {
  const int i = blockIdx.x;
  const int r = rank[i];
  if (r < 0) return;
  const float g = tanhf(y[i]);
  out0[(size_t)r * F_DIM + threadIdx.x] = X[(size_t)i * F_DIM + threadIdx.x] * g;
}

// ---------------- C[m,n] = sum_k A8[m,k] * B8[n,k] (fp8 MX, scale=1.0) ----------------
// LDS layout: row r (128 B) split into 8 16-B subchunks; global subchunk s
// stored at slot r*8 + (s ^ (r&7)). Staging stays lane-contiguous for
// global_load_lds; ds_read_b128 spreads lanes across bank groups.
// 2-phase pipeline: double-buffered LDS, raw s_barrier, counted vmcnt(8) so
// the next tile's 8 DMA loads stay in flight across the barrier.
#define BM  128
#define BN  128
#define BKB 128  // K elements (=bytes) per tile
#define BUFA (BM * BKB)
#define BUFB (BN * BKB)

__global__ __launch_bounds__(256) void gemm_fp8(const unsigned char* __restrict__ A,
                                                const unsigned char* __restrict__ B,
                                                float* __restrict__ C) {
  const int Kd = N_NODES;  // 8192
  const int Nd = K_SEL;    // 4096
  __shared__ unsigned char sA[2][BUFA];  // 32 KB
  __shared__ unsigned char sB[2][BUFB];  // 32 KB
  const int tid = threadIdx.x;
  const int wave = tid >> 6, lane = tid & 63;
  const int m0 = blockIdx.x * BM, n0 = blockIdx.y * BN;
  const int wm = (wave >> 1) * 64, wn = (wave & 1) * 64;

  // staging: copy i handles 16B slot S = i*256 + tid (LDS dest = wave-uniform
  // base + lane*16; swizzle applied on the global source address)
  const unsigned char* Ag[4];
  const unsigned char* Bg[4];
  int ldsOff[4];
  #pragma unroll
  for (int i = 0; i < 4; ++i) {
    int S = i * 256 + tid;
    int r = S >> 3;
    int sg = (S & 7) ^ (r & 7);
    Ag[i] = A + (size_t)(m0 + r) * Kd + sg * 16;
    Bg[i] = B + (size_t)(n0 + r) * Kd + sg * 16;
    ldsOff[i] = i * 4096 + wave * 1024;
  }

  floatx4 acc[4][4] = {};

  const int l15 = lane & 15, q = lane >> 4;
  // A-frag (16x16x128): row = lane&15, k = q*32 + j (32 consecutive bytes)
  int offAlo[4], offAhi[4], offBlo[4], offBhi[4];
  #pragma unroll
  for (int t = 0; t < 4; ++t) {
    int RA = wm + t * 16 + l15;
    int RB = wn + t * 16 + l15;
    offAlo[t] = RA * 128 + (((2 * q) ^ (RA & 7)) << 4);
    offAhi[t] = RA * 128 + (((2 * q + 1) ^ (RA & 7)) << 4);
    offBlo[t] = RB * 128 + (((2 * q) ^ (RB & 7)) << 4);
    offBhi[t] = RB * 128 + (((2 * q + 1) ^ (RB & 7)) << 4);
  }

  // prologue: stage tile 0 into buffer 0
  #pragma unroll
  for (int i = 0; i < 4; ++i) {
    async_copy16(Ag[i], (char*)sA + ldsOff[i]);
    async_copy16(Bg[i], (char*)sB + ldsOff[i]);
  }

  int cur = 0;
  for (int kt = 0; kt < Kd; kt += BKB) {
    const bool last = (kt + BKB >= Kd);
    if (!last) {
      const int nxt = cur ^ 1;
      #pragma unroll
      for (int i = 0; i < 4; ++i) {
        async_copy16(Ag[i] + kt + BKB, (char*)sA + nxt * BUFA + ldsOff[i]);
        async_copy16(Bg[i] + kt + BKB, (char*)sB + nxt * BUFB + ldsOff[i]);
      }
      // wait for THIS tile's 8 loads only; next tile's 8 stay in flight
      asm volatile("s_waitcnt vmcnt(8)" ::: "memory");
    } else {
      asm volatile("s_waitcnt vmcnt(0)" ::: "memory");
    }
    __builtin_amdgcn_s_barrier();
    asm volatile("" ::: "memory");

    const char* bA = (const char*)sA + cur * BUFA;
    const char* bB = (const char*)sB + cur * BUFB;
    intx8 av[4], bv[4];
    #pragma unroll
    for (int t = 0; t < 4; ++t) {
      intx4 lo = *(const intx4*)(bA + offAlo[t]);
      intx4 hi = *(const intx4*)(bA + offAhi[t]);
      av[t] = __builtin_shufflevector(lo, hi, 0, 1, 2, 3, 4, 5, 6, 7);
      lo = *(const intx4*)(bB + offBlo[t]);
      hi = *(const intx4*)(bB + offBhi[t]);
      bv[t] = __builtin_shufflevector(lo, hi, 0, 1, 2, 3, 4, 5, 6, 7);
    }
    __builtin_amdgcn_s_setprio(1);
    #pragma unroll
    for (int tm = 0; tm < 4; ++tm)
      #pragma unroll
      for (int tn = 0; tn < 4; ++tn)
        acc[tm][tn] = __builtin_amdgcn_mfma_scale_f32_16x16x128_f8f6f4(
            av[tm], bv[tn], acc[tm][tn],
            0, 0,                    // cbsz=fp8(e4m3), blgp=fp8(e4m3)
            0, 0x7F7F7F7F,           // scale_a opsel, scale_a = 1.0 (e8m0 127)
            0, 0x7F7F7F7F);          // scale_b opsel, scale_b = 1.0
    __builtin_amdgcn_s_setprio(0);
    // drain this wave's ds_reads before any wave's next-tile DMA can
    // overwrite this buffer (two tiles from now)
    asm volatile("s_waitcnt lgkmcnt(0)" ::: "memory");
    __builtin_amdgcn_s_barrier();
    asm volatile("" ::: "memory");
    cur ^= 1;
  }

  // C/D layout (shape-determined): col = lane&15, row = (lane>>4)*4 + reg
  const int cm = (lane >> 4) * 4;
  const int cn = lane & 15;
  #pragma unroll
  for (int tm = 0; tm < 4; ++tm)
    #pragma unroll
    for (int tn = 0; tn < 4; ++tn) {
      float* cp = C + (size_t)(m0 + wm + tm * 16 + cm) * Nd + (n0 + wn + tn * 16 + cn);
      #pragma unroll
      for (int r = 0; r < 4; ++r) cp[(size_t)r * Nd] = acc[tm][tn][r];
    }
}

extern "C" void kernel_launch(void* const* d_in, const int* in_sizes, int n_in,
                              void* d_out, int out_size, void* d_ws, size_t ws_size,
                              hipStream_t stream) {
  const float* X = (const float*)d_in[0];
  const float* A = (const float*)d_in[1];
  const float* p = (const float*)d_in[2];
  float* out0 = (float*)d_out;                      // X_pooled 4096x256
  float* out1 = out0 + (size_t)K_SEL * F_DIM;       // A_pooled 4096x4096

  // ws layout: y (32KB) | rank (32KB) | Abf8 (32MB) | Bt8 (32MB)
  char* ws = (char*)d_ws;
  float* y = (float*)ws;
  int* rank = (int*)(ws + 32768);
  unsigned char* Abf8 = (unsigned char*)(ws + 65536);
  unsigned char* Bt8 = Abf8 + (size_t)K_SEL * N_NODES;

  compute_y<<<N_NODES / 4, 256, 0, stream>>>(X, p, y);
  topk_radix<<<1, 1024, 0, stream>>>(y, rank);
  x_pool<<<N_NODES, 256, 0, stream>>>(X, y, rank, out0);
  gather_both<<<dim3(N_NODES / 64, N_NODES / 64), 256, 0, stream>>>(A, rank, Abf8, Bt8);
  gemm_fp8<<<dim3(K_SEL / BM, K_SEL / BN), 256, 0, stream>>>(Abf8, Bt8, out1);
}